// Round 12
// baseline (236.682 us; speedup 1.0000x reference)
//
#include <hip/hip_runtime.h>
#include <hip/hip_fp16.h>
#include <cstdint>
#include <cstddef>

#define DIM_IN 128
#define DIM_HID 64
#define MS_TILE 2048      // edges per multisplit tile
#define MS_WGS 1024       // msplit workgroups
#define OVF_CAP 32768     // overflow valve capacity (edges)
#define BSH 8             // bin shift: 256-node bins
#define BINSZ 256
#define MAXNB 512
#define CAPL 10240        // LDS-staged edges per bin (40KB); mean 8184, ~20 sigma

// native clang vectors (nontemporal builtins reject HIP_vector_type classes)
typedef int v2i __attribute__((ext_vector_type(2)));

// ---------- edge dtype detection: int32 (stride 1) vs int64 (stride 2) ----------
__global__ void k_detect(const int* __restrict__ e, int* __restrict__ flag) {
    if (blockIdx.x == 0 && threadIdx.x == 0) {
        int o = 0;
        for (int j = 1; j < 128; j += 2) o |= e[j];
        flag[0] = (o == 0) ? 2 : 1;
    }
}

// ---------- multisplit: eidx -> 391 dst-bins of packed (src<<8|ldst) words ----------
__global__ __launch_bounds__(256) void k_msplit2(const int* __restrict__ eidx,
                                                 const int* __restrict__ flag,
                                                 int* __restrict__ binCursor,
                                                 unsigned int* __restrict__ binned,
                                                 int* __restrict__ ovfCnt,
                                                 v2i* __restrict__ ovf,
                                                 int E, int NB, int cap) {
    __shared__ int hist[MAXNB], base[MAXNB], scanb[MAXNB], s4[128];
    __shared__ v2i buf[MS_TILE];  // {packed word, bin}
    int t = threadIdx.x;
    int st = flag[0];
    int ntiles = (E + MS_TILE - 1) / MS_TILE;

    for (int tile = blockIdx.x; tile < ntiles; tile += gridDim.x) {
        int e0 = tile * MS_TILE;
        int cntE = min(MS_TILE, E - e0);

        unsigned int words[8];
        int bins[8];
#pragma unroll
        for (int j = 0; j < 8; j++) {
            int e = e0 + t + 256 * j;
            if (e < E) {
                int s, d;
                if (st == 2) {
                    v2i a = __builtin_nontemporal_load((const v2i*)eidx + e);
                    v2i b = __builtin_nontemporal_load((const v2i*)eidx + E + e);
                    s = a.x; d = b.x;
                } else {
                    s = __builtin_nontemporal_load(&eidx[e]);
                    d = __builtin_nontemporal_load(&eidx[E + e]);
                }
                words[j] = ((unsigned int)s << BSH) | (unsigned int)(d & (BINSZ - 1));
                bins[j] = d >> BSH;
            } else {
                bins[j] = -1;
            }
        }

        hist[t] = 0; hist[t + 256] = 0;
        __syncthreads();
#pragma unroll
        for (int j = 0; j < 8; j++)
            if (bins[j] >= 0) atomicAdd(&hist[bins[j]], 1);
        __syncthreads();
        // 2-level exclusive scan over <=512 bins
        if (t < 128)
            s4[t] = hist[4 * t] + hist[4 * t + 1] + hist[4 * t + 2] + hist[4 * t + 3];
        __syncthreads();
        if (t == 0) {
            int run = 0;
            for (int b = 0; b < 128; b++) { int v = s4[b]; s4[b] = run; run += v; }
        }
        __syncthreads();
        if (t < 128) {
            int r = s4[t];
#pragma unroll
            for (int j = 0; j < 4; j++) { scanb[4 * t + j] = r; r += hist[4 * t + j]; }
        }
        __syncthreads();
        for (int b = t; b < NB; b += 256)
            if (hist[b] > 0) base[b] = atomicAdd(&binCursor[b], hist[b]);
        __syncthreads();
        hist[t] = 0; hist[t + 256] = 0;   // reuse as rank counters
        __syncthreads();
#pragma unroll
        for (int j = 0; j < 8; j++) {
            if (bins[j] >= 0) {
                int r = atomicAdd(&hist[bins[j]], 1);
                buf[scanb[bins[j]] + r] = (v2i){(int)words[j], bins[j]};
            }
        }
        __syncthreads();
        for (int j = t; j < cntE; j += 256) {
            v2i p = buf[j];
            int b = p.y;
            int local = base[b] + (j - scanb[b]);
            if (local < cap) {
                binned[(size_t)b * cap + local] = (unsigned int)p.x;
            } else {
                int o = atomicAdd(ovfCnt, 1);
                if (o < OVF_CAP)
                    ovf[o] = (v2i){(int)((unsigned int)p.x >> BSH),
                                   (b << BSH) | (p.x & (BINSZ - 1))};
            }
        }
        __syncthreads();
    }
}

// ---------- per-bin degree histogram in LDS (no global atomics) ----------
__global__ __launch_bounds__(256) void k_binhist(const unsigned int* __restrict__ binned,
                                                 const int* __restrict__ binCursor,
                                                 int* __restrict__ cnt,
                                                 int cap, int N) {
    __shared__ int hist[BINSZ];
    int b = blockIdx.x;
    int t = threadIdx.x;
    hist[t] = 0;
    __syncthreads();
    int n = min(binCursor[b], cap);
    const unsigned int* p = binned + (size_t)b * cap;
    for (int i = t; i < n; i += 256) {
        unsigned int w = __builtin_nontemporal_load(p + i);
        atomicAdd(&hist[w & (BINSZ - 1)], 1);
    }
    __syncthreads();
    int g = b * BINSZ + t;
    if (g < N) cnt[g] = hist[t];
}

// ---------- scan S1: per-1024-chunk sums; also dinv = rsqrt(cnt+1) ----------
__global__ __launch_bounds__(1024) void k_s1(const int* __restrict__ cnt,
                                             float* __restrict__ dinv,
                                             int* __restrict__ bsum, int N) {
    __shared__ int sh[1024];
    int t = threadIdx.x;
    int i = blockIdx.x * 1024 + t;
    int c = (i < N) ? cnt[i] : 0;
    if (i < N) dinv[i] = rsqrtf((float)(c + 1));
    sh[t] = c;
    __syncthreads();
    for (int d = 512; d > 0; d >>= 1) {
        if (t < d) sh[t] += sh[t + d];
        __syncthreads();
    }
    if (t == 0) bsum[blockIdx.x] = sh[0];
}

__global__ void k_s2(int* __restrict__ bsum, int NB) {
    if (blockIdx.x == 0 && threadIdx.x == 0) {
        int run = 0;
        for (int b = 0; b < NB; b++) { int v = bsum[b]; bsum[b] = run; run += v; }
    }
}

__global__ __launch_bounds__(1024) void k_s3(const int* __restrict__ cnt,
                                             const int* __restrict__ bsum,
                                             int* __restrict__ offsets,
                                             int* __restrict__ cursor, int N) {
    __shared__ int sh[1024];
    int t = threadIdx.x;
    int i = blockIdx.x * 1024 + t;
    int c = (i < N) ? cnt[i] : 0;
    sh[t] = c;
    __syncthreads();
    for (int d = 1; d < 1024; d <<= 1) {
        int add = (t >= d) ? sh[t - d] : 0;
        __syncthreads();
        sh[t] += add;
        __syncthreads();
    }
    if (i < N) {
        int incl = bsum[blockIdx.x] + sh[t];
        offsets[i + 1] = incl;
        cursor[i] = incl - c;
    }
    if (i == 0) offsets[0] = 0;
}

// ---------- CSR fill: LDS-staged payload, coalesced flush ----------
__global__ __launch_bounds__(256) void k_fillL(const unsigned int* __restrict__ binned,
                                               const int* __restrict__ binCursor,
                                               const int* __restrict__ offsets,
                                               int* __restrict__ cursor,
                                               int* __restrict__ csr,
                                               int cap, int N) {
    __shared__ int curL[BINSZ];
    __shared__ unsigned int stage[CAPL];
    int b = blockIdx.x;
    int t = threadIdx.x;
    int g0 = b << BSH;
    int g = g0 + t;
    int binBase = offsets[g0];
    int sliceEnd = offsets[min(g0 + BINSZ, N)];
    curL[t] = (g < N) ? offsets[g] - binBase : 0;
    __syncthreads();

    int n = min(binCursor[b], cap);
    const unsigned int* p = binned + (size_t)b * cap;
    int nl = min(n, CAPL);
    for (int i = t; i < nl; i += 256) {
        unsigned int w = __builtin_nontemporal_load(p + i);
        int pos = atomicAdd(&curL[w & (BINSZ - 1)], 1);
        stage[pos] = w >> BSH;
    }
    __syncthreads();

    if (g < N) cursor[g] = binBase + curL[t];   // write back (tail + k_ovf)
    int slice = sliceEnd - binBase;
    for (int i = t; i < slice; i += 256)
        csr[binBase + i] = (int)stage[i];       // coalesced flush
    __syncthreads();
    for (int i = CAPL + t; i < n; i += 256) {   // tail (statistically never)
        unsigned int w = p[i];
        int pos = atomicAdd(&cursor[g0 + (int)(w & (BINSZ - 1))], 1);
        csr[pos] = (int)(w >> BSH);
    }
}

// ---------- drain overflow valve (normally 0 edges) ----------
__global__ void k_ovf(const int* __restrict__ ovfCnt, const v2i* __restrict__ ovf,
                      int* __restrict__ cursor, int* __restrict__ csr) {
    int n = min(*ovfCnt, OVF_CAP);
    for (int i = threadIdx.x; i < n; i += 256) {
        v2i e = ovf[i];
        int pos = atomicAdd(&cursor[e.y], 1);
        csr[pos] = e.x;
    }
}

// ---------- GEMM1: h1' = (x @ W1) * dinv[row], fp16-packed [N,32] __half2 ----------
// (R10 post-mortem: phase-major split was request-rate bound; reverted to the
// row-major 128B-gather layout.)
__global__ __launch_bounds__(256) void k_gemm1t(const float* __restrict__ x,
                                                const float* __restrict__ W,
                                                const float* __restrict__ dinv,
                                                __half2* __restrict__ h1, int N) {
    __shared__ float xsT[DIM_IN * 64];      // [k][row] transposed tile, 32KB
    __shared__ float Ws[DIM_IN * DIM_HID];  // [k][col], 32KB
    int t = threadIdx.x;
    int row0 = blockIdx.x * 64;

#pragma unroll
    for (int i = 0; i < 8; i++)
        ((float4*)Ws)[t + 256 * i] = ((const float4*)W)[t + 256 * i];

#pragma unroll
    for (int i = 0; i < 8; i++) {
        int idx = t * 8 + i;
        int r = idx >> 5;
        int kc = idx & 31;
        int row = row0 + r;
        float4 v = (row < N) ? ((const float4*)(x + (size_t)row * DIM_IN))[kc]
                             : make_float4(0.f, 0.f, 0.f, 0.f);
        xsT[(4 * kc + 0) * 64 + r] = v.x;
        xsT[(4 * kc + 1) * 64 + r] = v.y;
        xsT[(4 * kc + 2) * 64 + r] = v.z;
        xsT[(4 * kc + 3) * 64 + r] = v.w;
    }
    __syncthreads();

    int c = t & 15;
    int r = t >> 4;
    float acc[4][4] = {};

#pragma unroll 4
    for (int k = 0; k < DIM_IN; k++) {
        float4 xa = *(const float4*)&xsT[k * 64 + 4 * r];
        float4 wb = *(const float4*)&Ws[k * DIM_HID + 4 * c];
#pragma unroll
        for (int i = 0; i < 4; i++) {
            float xi = (i == 0) ? xa.x : (i == 1) ? xa.y : (i == 2) ? xa.z : xa.w;
            acc[i][0] = fmaf(xi, wb.x, acc[i][0]);
            acc[i][1] = fmaf(xi, wb.y, acc[i][1]);
            acc[i][2] = fmaf(xi, wb.z, acc[i][2]);
            acc[i][3] = fmaf(xi, wb.w, acc[i][3]);
        }
    }

#pragma unroll
    for (int i = 0; i < 4; i++) {
        int row = row0 + 4 * r + i;
        if (row < N) {
            float d = dinv[row];
            h1[(size_t)row * 32 + 2 * c] = __floats2half2_rn(acc[i][0] * d, acc[i][1] * d);
            h1[(size_t)row * 32 + 2 * c + 1] = __floats2half2_rn(acc[i][2] * d, acc[i][3] * d);
        }
    }
}

// ---------- agg1: g = relu(di*(sum h1'[src] + h1'[node]) + b1); h2' = (g@W2)*di ----------
// Half-wave per node (128B row gather) + fp16 __hadd2 accumulation (validated
// numerically by R10: identical absmax). Per edge-lane: 1 load + 1 v_pk_add_f16.
__global__ __launch_bounds__(256) void k_agg1(const __half2* __restrict__ h1,
                                              const int* __restrict__ csr,
                                              const int* __restrict__ offsets,
                                              const float* __restrict__ dinv,
                                              const float* __restrict__ b1,
                                              const float* __restrict__ W2,
                                              float4* __restrict__ h2, int N) {
    int t = threadIdx.x;
    int hl = t & 31;
    int node = blockIdx.x * 8 + (t >> 5);
    if (node >= N) return;

    float di = dinv[node];
    int beg = offsets[node], end = offsets[node + 1];
    __half2 a0 = h1[(size_t)node * 32 + hl];   // self-loop (pre-scaled)
    __half2 a1 = __floats2half2_rn(0.f, 0.f);

    int e = beg;
    for (; e + 3 < end; e += 4) {
        int s0 = csr[e], s1 = csr[e + 1], s2 = csr[e + 2], s3 = csr[e + 3];
        a0 = __hadd2(a0, h1[(size_t)s0 * 32 + hl]);
        a1 = __hadd2(a1, h1[(size_t)s1 * 32 + hl]);
        a0 = __hadd2(a0, h1[(size_t)s2 * 32 + hl]);
        a1 = __hadd2(a1, h1[(size_t)s3 * 32 + hl]);
    }
    for (; e < end; e++)
        a0 = __hadd2(a0, h1[(size_t)csr[e] * 32 + hl]);

    float2 f0 = __half22float2(a0);
    float2 f1 = __half22float2(a1);
    float accx = f0.x + f1.x, accy = f0.y + f1.y;

    float2 bb = ((const float2*)b1)[hl];
    float gx = fmaxf(fmaf(accx, di, bb.x), 0.f);
    float gy = fmaxf(fmaf(accy, di, bb.y), 0.f);

    const float* w0 = W2 + (2 * hl) * 3;
    const float* w1 = W2 + (2 * hl + 1) * 3;
    float v0 = gx * w0[0] + gy * w1[0];
    float v1 = gx * w0[1] + gy * w1[1];
    float v2 = gx * w0[2] + gy * w1[2];
#pragma unroll
    for (int off = 16; off > 0; off >>= 1) {
        v0 += __shfl_xor(v0, off, 64);
        v1 += __shfl_xor(v1, off, 64);
        v2 += __shfl_xor(v2, off, 64);
    }
    if (hl == 0) h2[node] = make_float4(v0 * di, v1 * di, v2 * di, 0.f);
}

// ---------- agg2: out = di*(sum h2'[src] + h2'[node]) + b2 ----------
__global__ __launch_bounds__(256) void k_agg2(const float4* __restrict__ h2,
                                              const int* __restrict__ csr,
                                              const int* __restrict__ offsets,
                                              const float* __restrict__ dinv,
                                              const float* __restrict__ b2,
                                              float* __restrict__ out, int N) {
    int t = threadIdx.x;
    int lane = t & 63;
    int node = blockIdx.x * 4 + (t >> 6);
    if (node >= N) return;

    float di = dinv[node];
    int beg = offsets[node], end = offsets[node + 1];
    float a0 = 0.f, a1 = 0.f, a2 = 0.f;
    for (int e = beg + lane; e < end; e += 64) {
        float4 h = h2[csr[e]];
        a0 += h.x;
        a1 += h.y;
        a2 += h.z;
    }
#pragma unroll
    for (int off = 32; off > 0; off >>= 1) {
        a0 += __shfl_xor(a0, off, 64);
        a1 += __shfl_xor(a1, off, 64);
        a2 += __shfl_xor(a2, off, 64);
    }
    if (lane == 0) {
        float4 hs = h2[node];
        out[(size_t)node * 3 + 0] = fmaf(a0 + hs.x, di, b2[0]);
        out[(size_t)node * 3 + 1] = fmaf(a1 + hs.y, di, b2[1]);
        out[(size_t)node * 3 + 2] = fmaf(a2 + hs.z, di, b2[2]);
    }
}

extern "C" void kernel_launch(void* const* d_in, const int* in_sizes, int n_in,
                              void* d_out, int out_size, void* d_ws, size_t ws_size,
                              hipStream_t stream) {
    const float* x = (const float*)d_in[0];
    const int* eidx = (const int*)d_in[1];
    const float* W1 = (const float*)d_in[2];
    const float* b1 = (const float*)d_in[3];
    const float* W2 = (const float*)d_in[4];
    const float* b2 = (const float*)d_in[5];
    float* out = (float*)d_out;

    const int N = in_sizes[0] / DIM_IN;   // 100000
    const int E = in_sizes[1] / 2;        // 3200000
    const int NB = (N + BINSZ - 1) >> BSH;  // 391 bins of 256 nodes

    char* w = (char*)d_ws;
    size_t off = 0;
    auto carve = [&](size_t bytes) -> char* {
        char* p = w + off;
        off += (bytes + 255) & ~(size_t)255;
        return p;
    };
    int* flag = (int*)carve(16);
    int* cnt = (int*)carve((size_t)N * 4);
    int* offsets = (int*)carve((size_t)(N + 1) * 4);
    int* cursor = (int*)carve((size_t)N * 4);
    int* bsum = (int*)carve(1024 * 4);
    float* dinv = (float*)carve((size_t)N * 4);
    int* csr = (int*)carve((size_t)E * 4);
    int* binCursor = (int*)carve(MAXNB * 4);
    int* ovfCnt = (int*)carve(16);
    v2i* ovf = (v2i*)carve((size_t)OVF_CAP * 8);
    float4* h2 = (float4*)carve((size_t)N * 16);

    // uni region: packed binned words (msplit..fillL), then aliased by fp16 h1'.
    size_t h1_bytes = (size_t)N * DIM_HID * 2;
    int capDes = E / NB + E / NB / 16 + 128;     // mean + margin
    size_t binned_des = (size_t)NB * capDes * 4;
    size_t uni_avail = (ws_size > off + 256) ? (ws_size - off - 256) : h1_bytes;
    size_t uni_bytes = binned_des > h1_bytes ? binned_des : h1_bytes;
    if (uni_bytes > uni_avail) uni_bytes = uni_avail > h1_bytes ? uni_avail : h1_bytes;
    char* uni = carve(uni_bytes);
    unsigned int* binned = (unsigned int*)uni;
    __half2* h1 = (__half2*)uni;        // aliased: valid only after k_fillL
    int cap = (int)(uni_bytes / ((size_t)NB * 4));
    if (cap > capDes) cap = capDes;

    (void)hipMemsetAsync(binCursor, 0, MAXNB * 4 + 256, stream);  // binCursor + ovfCnt
    k_detect<<<1, 64, 0, stream>>>(eidx, flag);

    k_msplit2<<<MS_WGS, 256, 0, stream>>>(eidx, flag, binCursor, binned,
                                          ovfCnt, ovf, E, NB, cap);
    k_binhist<<<NB, 256, 0, stream>>>(binned, binCursor, cnt, cap, N);

    int NBLK = (N + 1023) / 1024;
    k_s1<<<NBLK, 1024, 0, stream>>>(cnt, dinv, bsum, N);
    k_s2<<<1, 64, 0, stream>>>(bsum, NBLK);
    k_s3<<<NBLK, 1024, 0, stream>>>(cnt, bsum, offsets, cursor, N);

    k_fillL<<<NB, 256, 0, stream>>>(binned, binCursor, offsets, cursor, csr, cap, N);
    k_ovf<<<1, 256, 0, stream>>>(ovfCnt, ovf, cursor, csr);

    k_gemm1t<<<(N + 63) / 64, 256, 0, stream>>>(x, W1, dinv, h1, N);
    k_agg1<<<(N + 7) / 8, 256, 0, stream>>>(h1, csr, offsets, dinv, b1, W2, h2, N);
    k_agg2<<<(N + 3) / 4, 256, 0, stream>>>(h2, csr, offsets, dinv, b2, out, N);
}

// Round 13
// 197.694 us; speedup vs baseline: 1.1972x; 1.1972x over previous
//
#include <hip/hip_runtime.h>
#include <hip/hip_fp16.h>
#include <cstdint>
#include <cstddef>

#define DIM_IN 128
#define DIM_HID 64
#define MS_TILE 4096      // edges per multisplit tile (R12: 2048->4096, halves run fragmentation)
#define OVF_CAP 32768     // overflow valve capacity (edges)
#define BSH 8             // bin shift: 256-node bins
#define BINSZ 256
#define MAXNB 512
#define CAPL 10240        // LDS stage (40KB); cap < CAPL by construction -> tail is dead code

// native clang vectors (nontemporal builtins reject HIP_vector_type classes)
typedef int v2i __attribute__((ext_vector_type(2)));

// ---------- edge dtype detection: int32 (stride 1) vs int64 (stride 2) ----------
__global__ void k_detect(const int* __restrict__ e, int* __restrict__ flag) {
    if (blockIdx.x == 0 && threadIdx.x == 0) {
        int o = 0;
        for (int j = 1; j < 128; j += 2) o |= e[j];
        flag[0] = (o == 0) ? 2 : 1;
    }
}

// ---------- multisplit: eidx -> 391 dst-bins of packed (src<<8|ldst) words ----------
__global__ __launch_bounds__(256) void k_msplit2(const int* __restrict__ eidx,
                                                 const int* __restrict__ flag,
                                                 int* __restrict__ binCursor,
                                                 unsigned int* __restrict__ binned,
                                                 int* __restrict__ ovfCnt,
                                                 v2i* __restrict__ ovf,
                                                 int E, int NB, int cap) {
    __shared__ int hist[MAXNB], base[MAXNB], scanb[MAXNB], s4[128];
    __shared__ v2i buf[MS_TILE];  // {packed word, bin}
    int t = threadIdx.x;
    int st = flag[0];
    int ntiles = (E + MS_TILE - 1) / MS_TILE;

    for (int tile = blockIdx.x; tile < ntiles; tile += gridDim.x) {
        int e0 = tile * MS_TILE;
        int cntE = min(MS_TILE, E - e0);

        unsigned int words[16];
        int bins[16];
#pragma unroll
        for (int j = 0; j < 16; j++) {
            int e = e0 + t + 256 * j;
            if (e < E) {
                int s, d;
                if (st == 2) {
                    v2i a = __builtin_nontemporal_load((const v2i*)eidx + e);
                    v2i b = __builtin_nontemporal_load((const v2i*)eidx + E + e);
                    s = a.x; d = b.x;
                } else {
                    s = __builtin_nontemporal_load(&eidx[e]);
                    d = __builtin_nontemporal_load(&eidx[E + e]);
                }
                words[j] = ((unsigned int)s << BSH) | (unsigned int)(d & (BINSZ - 1));
                bins[j] = d >> BSH;
            } else {
                bins[j] = -1;
            }
        }

        hist[t] = 0; hist[t + 256] = 0;
        __syncthreads();
#pragma unroll
        for (int j = 0; j < 16; j++)
            if (bins[j] >= 0) atomicAdd(&hist[bins[j]], 1);
        __syncthreads();
        // 2-level exclusive scan over <=512 bins
        if (t < 128)
            s4[t] = hist[4 * t] + hist[4 * t + 1] + hist[4 * t + 2] + hist[4 * t + 3];
        __syncthreads();
        if (t == 0) {
            int run = 0;
            for (int b = 0; b < 128; b++) { int v = s4[b]; s4[b] = run; run += v; }
        }
        __syncthreads();
        if (t < 128) {
            int r = s4[t];
#pragma unroll
            for (int j = 0; j < 4; j++) { scanb[4 * t + j] = r; r += hist[4 * t + j]; }
        }
        __syncthreads();
        for (int b = t; b < NB; b += 256)
            if (hist[b] > 0) base[b] = atomicAdd(&binCursor[b], hist[b]);
        __syncthreads();
        hist[t] = 0; hist[t + 256] = 0;   // reuse as rank counters
        __syncthreads();
#pragma unroll
        for (int j = 0; j < 16; j++) {
            if (bins[j] >= 0) {
                int r = atomicAdd(&hist[bins[j]], 1);
                buf[scanb[bins[j]] + r] = (v2i){(int)words[j], bins[j]};
            }
        }
        __syncthreads();
        for (int j = t; j < cntE; j += 256) {
            v2i p = buf[j];
            int b = p.y;
            int local = base[b] + (j - scanb[b]);
            if (local < cap) {
                binned[(size_t)b * cap + local] = (unsigned int)p.x;
            } else {
                int o = atomicAdd(ovfCnt, 1);
                if (o < OVF_CAP)
                    ovf[o] = (v2i){(int)((unsigned int)p.x >> BSH),
                                   (b << BSH) | (p.x & (BINSZ - 1))};
            }
        }
        __syncthreads();
    }
}

// ---------- exclusive scan of bin totals -> binBase ----------
__global__ __launch_bounds__(512) void k_binscan(const int* __restrict__ binCursor,
                                                 int* __restrict__ binBase,
                                                 int NB, int cap) {
    __shared__ int sh[512];
    int t = threadIdx.x;
    int v = (t < NB) ? min(binCursor[t], cap) : 0;
    sh[t] = v;
    __syncthreads();
    for (int d = 1; d < 512; d <<= 1) {
        int add = (t >= d) ? sh[t - d] : 0;
        __syncthreads();
        sh[t] += add;
        __syncthreads();
    }
    if (t < NB) binBase[t] = sh[t] - v;
}

// ---------- fused fill: hist + scan -> offsets/dinv/cursor; stage + flush csr ----------
// Replaces binhist+s1+s2+s3+fillL (R12): one pass computes per-node degree in
// LDS, scans it, emits offsets/dinv, then places edges in LDS stage and
// flushes the bin's csr slice coalesced. n <= cap < CAPL by construction.
__global__ __launch_bounds__(256) void k_fillA(const unsigned int* __restrict__ binned,
                                               const int* __restrict__ binCursor,
                                               const int* __restrict__ binBase,
                                               int* __restrict__ offsets,
                                               int* __restrict__ cursor,
                                               float* __restrict__ dinv,
                                               int* __restrict__ csr,
                                               int cap, int N) {
    __shared__ int hist[BINSZ], scanS[BINSZ], curL[BINSZ];
    __shared__ unsigned int stage[CAPL];
    int b = blockIdx.x;
    int t = threadIdx.x;
    int g0 = b << BSH;
    int g = g0 + t;
    int n = min(binCursor[b], cap);
    const unsigned int* p = binned + (size_t)b * cap;

    hist[t] = 0;
    __syncthreads();
    for (int i = t; i < n; i += 256)
        atomicAdd(&hist[__builtin_nontemporal_load(p + i) & (BINSZ - 1)], 1);
    __syncthreads();
    int h = hist[t];
    scanS[t] = h;
    __syncthreads();
    for (int d = 1; d < 256; d <<= 1) {
        int add = (t >= d) ? scanS[t - d] : 0;
        __syncthreads();
        scanS[t] += add;
        __syncthreads();
    }
    int excl = scanS[t] - h;
    int gbase = binBase[b];
    if (g < N) {
        offsets[g] = gbase + excl;
        dinv[g] = rsqrtf((float)(h + 1));
    }
    if (t == 255) offsets[min(g0 + BINSZ, N)] = gbase + scanS[255];  // race-benign dup

    curL[t] = excl;
    __syncthreads();
    int nl = min(n, CAPL);
    for (int i = t; i < nl; i += 256) {
        unsigned int w = __builtin_nontemporal_load(p + i);
        int pos = atomicAdd(&curL[w & (BINSZ - 1)], 1);
        if (pos < CAPL) stage[pos] = w >> BSH;
    }
    __syncthreads();
    if (g < N) cursor[g] = gbase + curL[t];     // final positions (ovf valve)
    for (int i = t; i < nl; i += 256)
        csr[gbase + i] = (int)stage[i];         // coalesced flush
    __syncthreads();
    for (int i = CAPL + t; i < n; i += 256) {   // dead by construction
        unsigned int w = p[i];
        int pos = atomicAdd(&cursor[g0 + (int)(w & (BINSZ - 1))], 1);
        csr[pos] = (int)(w >> BSH);
    }
}

// ---------- drain overflow valve (normally 0 edges) ----------
__global__ void k_ovf(const int* __restrict__ ovfCnt, const v2i* __restrict__ ovf,
                      int* __restrict__ cursor, int* __restrict__ csr) {
    int n = min(*ovfCnt, OVF_CAP);
    for (int i = threadIdx.x; i < n; i += 256) {
        v2i e = ovf[i];
        int pos = atomicAdd(&cursor[e.y], 1);
        csr[pos] = e.x;
    }
}

// ---------- GEMM1: h1' = (x @ W1) * dinv[row], fp16-packed [N,32] __half2 ----------
__global__ __launch_bounds__(256) void k_gemm1t(const float* __restrict__ x,
                                                const float* __restrict__ W,
                                                const float* __restrict__ dinv,
                                                __half2* __restrict__ h1, int N) {
    __shared__ float xsT[DIM_IN * 64];      // [k][row] transposed tile, 32KB
    __shared__ float Ws[DIM_IN * DIM_HID];  // [k][col], 32KB
    int t = threadIdx.x;
    int row0 = blockIdx.x * 64;

#pragma unroll
    for (int i = 0; i < 8; i++)
        ((float4*)Ws)[t + 256 * i] = ((const float4*)W)[t + 256 * i];

#pragma unroll
    for (int i = 0; i < 8; i++) {
        int idx = t * 8 + i;
        int r = idx >> 5;
        int kc = idx & 31;
        int row = row0 + r;
        float4 v = (row < N) ? ((const float4*)(x + (size_t)row * DIM_IN))[kc]
                             : make_float4(0.f, 0.f, 0.f, 0.f);
        xsT[(4 * kc + 0) * 64 + r] = v.x;
        xsT[(4 * kc + 1) * 64 + r] = v.y;
        xsT[(4 * kc + 2) * 64 + r] = v.z;
        xsT[(4 * kc + 3) * 64 + r] = v.w;
    }
    __syncthreads();

    int c = t & 15;
    int r = t >> 4;
    float acc[4][4] = {};

#pragma unroll 4
    for (int k = 0; k < DIM_IN; k++) {
        float4 xa = *(const float4*)&xsT[k * 64 + 4 * r];
        float4 wb = *(const float4*)&Ws[k * DIM_HID + 4 * c];
#pragma unroll
        for (int i = 0; i < 4; i++) {
            float xi = (i == 0) ? xa.x : (i == 1) ? xa.y : (i == 2) ? xa.z : xa.w;
            acc[i][0] = fmaf(xi, wb.x, acc[i][0]);
            acc[i][1] = fmaf(xi, wb.y, acc[i][1]);
            acc[i][2] = fmaf(xi, wb.z, acc[i][2]);
            acc[i][3] = fmaf(xi, wb.w, acc[i][3]);
        }
    }

#pragma unroll
    for (int i = 0; i < 4; i++) {
        int row = row0 + 4 * r + i;
        if (row < N) {
            float d = dinv[row];
            h1[(size_t)row * 32 + 2 * c] = __floats2half2_rn(acc[i][0] * d, acc[i][1] * d);
            h1[(size_t)row * 32 + 2 * c + 1] = __floats2half2_rn(acc[i][2] * d, acc[i][3] * d);
        }
    }
}

// ---------- agg1: g = relu(di*(sum h1'[src] + h1'[node]) + b1); h2' = (g@W2)*di ----------
// Half-wave per node. R12: one coalesced csr load per 32 edges + __shfl
// broadcast (LDS pipe) -> VMEM requests/edge 2 -> ~1.
__global__ __launch_bounds__(256) void k_agg1(const __half2* __restrict__ h1,
                                              const int* __restrict__ csr,
                                              const int* __restrict__ offsets,
                                              const float* __restrict__ dinv,
                                              const float* __restrict__ b1,
                                              const float* __restrict__ W2,
                                              float4* __restrict__ h2, int N) {
    int t = threadIdx.x;
    int hl = t & 31;
    int node = blockIdx.x * 8 + (t >> 5);
    if (node >= N) return;

    float di = dinv[node];
    int beg = offsets[node], end = offsets[node + 1];
    __half2 a0 = h1[(size_t)node * 32 + hl];   // self-loop (pre-scaled)
    __half2 a1 = __floats2half2_rn(0.f, 0.f);

    for (int base = beg; base < end; base += 32) {
        int rem = min(32, end - base);
        int sidx = (hl < rem) ? csr[base + hl] : 0;
        if (rem == 32) {
#pragma unroll 8
            for (int j = 0; j < 32; j += 4) {
                int s0 = __shfl(sidx, j, 32);
                int s1 = __shfl(sidx, j + 1, 32);
                int s2 = __shfl(sidx, j + 2, 32);
                int s3 = __shfl(sidx, j + 3, 32);
                a0 = __hadd2(a0, h1[(size_t)s0 * 32 + hl]);
                a1 = __hadd2(a1, h1[(size_t)s1 * 32 + hl]);
                a0 = __hadd2(a0, h1[(size_t)s2 * 32 + hl]);
                a1 = __hadd2(a1, h1[(size_t)s3 * 32 + hl]);
            }
        } else {
            int j = 0;
            for (; j + 1 < rem; j += 2) {
                int s0 = __shfl(sidx, j, 32);
                int s1 = __shfl(sidx, j + 1, 32);
                a0 = __hadd2(a0, h1[(size_t)s0 * 32 + hl]);
                a1 = __hadd2(a1, h1[(size_t)s1 * 32 + hl]);
            }
            if (j < rem) {
                int s0 = __shfl(sidx, j, 32);
                a0 = __hadd2(a0, h1[(size_t)s0 * 32 + hl]);
            }
        }
    }

    float2 f0 = __half22float2(a0);
    float2 f1 = __half22float2(a1);
    float accx = f0.x + f1.x, accy = f0.y + f1.y;

    float2 bb = ((const float2*)b1)[hl];
    float gx = fmaxf(fmaf(accx, di, bb.x), 0.f);
    float gy = fmaxf(fmaf(accy, di, bb.y), 0.f);

    const float* w0 = W2 + (2 * hl) * 3;
    const float* w1 = W2 + (2 * hl + 1) * 3;
    float v0 = gx * w0[0] + gy * w1[0];
    float v1 = gx * w0[1] + gy * w1[1];
    float v2 = gx * w0[2] + gy * w1[2];
#pragma unroll
    for (int off = 16; off > 0; off >>= 1) {
        v0 += __shfl_xor(v0, off, 64);
        v1 += __shfl_xor(v1, off, 64);
        v2 += __shfl_xor(v2, off, 64);
    }
    if (hl == 0) h2[node] = make_float4(v0 * di, v1 * di, v2 * di, 0.f);
}

// ---------- agg2: out = di*(sum h2'[src] + h2'[node]) + b2 ----------
__global__ __launch_bounds__(256) void k_agg2(const float4* __restrict__ h2,
                                              const int* __restrict__ csr,
                                              const int* __restrict__ offsets,
                                              const float* __restrict__ dinv,
                                              const float* __restrict__ b2,
                                              float* __restrict__ out, int N) {
    int t = threadIdx.x;
    int lane = t & 63;
    int node = blockIdx.x * 4 + (t >> 6);
    if (node >= N) return;

    float di = dinv[node];
    int beg = offsets[node], end = offsets[node + 1];
    float a0 = 0.f, a1 = 0.f, a2 = 0.f;
    for (int e = beg + lane; e < end; e += 64) {
        float4 h = h2[csr[e]];
        a0 += h.x;
        a1 += h.y;
        a2 += h.z;
    }
#pragma unroll
    for (int off = 32; off > 0; off >>= 1) {
        a0 += __shfl_xor(a0, off, 64);
        a1 += __shfl_xor(a1, off, 64);
        a2 += __shfl_xor(a2, off, 64);
    }
    if (lane == 0) {
        float4 hs = h2[node];
        out[(size_t)node * 3 + 0] = fmaf(a0 + hs.x, di, b2[0]);
        out[(size_t)node * 3 + 1] = fmaf(a1 + hs.y, di, b2[1]);
        out[(size_t)node * 3 + 2] = fmaf(a2 + hs.z, di, b2[2]);
    }
}

extern "C" void kernel_launch(void* const* d_in, const int* in_sizes, int n_in,
                              void* d_out, int out_size, void* d_ws, size_t ws_size,
                              hipStream_t stream) {
    const float* x = (const float*)d_in[0];
    const int* eidx = (const int*)d_in[1];
    const float* W1 = (const float*)d_in[2];
    const float* b1 = (const float*)d_in[3];
    const float* W2 = (const float*)d_in[4];
    const float* b2 = (const float*)d_in[5];
    float* out = (float*)d_out;

    const int N = in_sizes[0] / DIM_IN;     // 100000
    const int E = in_sizes[1] / 2;          // 3200000
    const int NB = (N + BINSZ - 1) >> BSH;  // 391 bins of 256 nodes

    char* w = (char*)d_ws;
    size_t off = 0;
    auto carve = [&](size_t bytes) -> char* {
        char* p = w + off;
        off += (bytes + 255) & ~(size_t)255;
        return p;
    };
    int* flag = (int*)carve(16);
    int* offsets = (int*)carve((size_t)(N + 1) * 4);
    int* cursor = (int*)carve((size_t)N * 4);
    float* dinv = (float*)carve((size_t)N * 4);
    int* csr = (int*)carve((size_t)E * 4);
    int* binCursor = (int*)carve(MAXNB * 4);
    int* ovfCnt = (int*)carve(16);
    v2i* ovf = (v2i*)carve((size_t)OVF_CAP * 8);
    int* binBase = (int*)carve(MAXNB * 4);
    float4* h2 = (float4*)carve((size_t)N * 16);

    // uni region: packed binned words (msplit..fillA), then aliased by fp16 h1'.
    size_t h1_bytes = (size_t)N * DIM_HID * 2;
    int capDes = E / NB + E / NB / 16 + 128;     // mean + margin; < CAPL by construction
    size_t binned_des = (size_t)NB * capDes * 4;
    size_t uni_avail = (ws_size > off + 256) ? (ws_size - off - 256) : h1_bytes;
    size_t uni_bytes = binned_des > h1_bytes ? binned_des : h1_bytes;
    if (uni_bytes > uni_avail) uni_bytes = uni_avail > h1_bytes ? uni_avail : h1_bytes;
    char* uni = carve(uni_bytes);
    unsigned int* binned = (unsigned int*)uni;
    __half2* h1 = (__half2*)uni;        // aliased: valid only after k_fillA
    int cap = (int)(uni_bytes / ((size_t)NB * 4));
    if (cap > capDes) cap = capDes;
    if (cap > CAPL) cap = CAPL;         // keep the fillA stage invariant

    (void)hipMemsetAsync(binCursor, 0, MAXNB * 4 + 256, stream);  // binCursor + ovfCnt
    k_detect<<<1, 64, 0, stream>>>(eidx, flag);

    int ntiles = (E + MS_TILE - 1) / MS_TILE;
    k_msplit2<<<ntiles, 256, 0, stream>>>(eidx, flag, binCursor, binned,
                                          ovfCnt, ovf, E, NB, cap);
    k_binscan<<<1, 512, 0, stream>>>(binCursor, binBase, NB, cap);
    k_fillA<<<NB, 256, 0, stream>>>(binned, binCursor, binBase, offsets, cursor,
                                    dinv, csr, cap, N);
    k_ovf<<<1, 256, 0, stream>>>(ovfCnt, ovf, cursor, csr);

    k_gemm1t<<<(N + 63) / 64, 256, 0, stream>>>(x, W1, dinv, h1, N);
    k_agg1<<<(N + 7) / 8, 256, 0, stream>>>(h1, csr, offsets, dinv, b1, W2, h2, N);
    k_agg2<<<(N + 3) / 4, 256, 0, stream>>>(h2, csr, offsets, dinv, b2, out, N);
}

// Round 14
// 193.053 us; speedup vs baseline: 1.2260x; 1.0240x over previous
//
#include <hip/hip_runtime.h>
#include <hip/hip_fp16.h>
#include <cstdint>
#include <cstddef>

#define DIM_IN 128
#define DIM_HID 64
#define MS_TILE 8192      // edges per multisplit tile (2-pass re-read design)
#define OVF_CAP 32768     // overflow valve capacity (edges)
#define BSH 8             // bin shift: 256-node bins
#define BINSZ 256
#define MAXNB 512
#define CAPL 10240        // LDS stage (40KB); cap < CAPL by construction -> tail is dead code

// native clang vectors (nontemporal builtins reject HIP_vector_type classes)
typedef int v2i __attribute__((ext_vector_type(2)));

// ---------- multisplit, 2-pass: hist+reserve, then re-read & place ----------
// R13 post-mortem: LDS-buffered variant held 54KB LDS + 80 VGPRs; this one
// re-reads the tile (L2-hot: 128KB/WG << 4MB) and writes runs (~130B) straight
// into reserved windows -- L2 fills the lines. dtype-detect folded in.
__global__ __launch_bounds__(256) void k_msplit3(const int* __restrict__ eidx,
                                                 int* __restrict__ binCursor,
                                                 unsigned int* __restrict__ binned,
                                                 int* __restrict__ ovfCnt,
                                                 v2i* __restrict__ ovf,
                                                 int E, int NB, int cap) {
    __shared__ int hist[MAXNB], base[MAXNB];
    __shared__ int stF;
    int t = threadIdx.x;
    if (t == 0) {           // int32 vs int64 detect (odd words of first 64 i64 all 0)
        int o = 0;
        for (int j = 1; j < 128; j += 2) o |= eidx[j];
        stF = (o == 0) ? 2 : 1;
    }
    __syncthreads();
    int st = stF;
    int ntiles = (E + MS_TILE - 1) / MS_TILE;

    for (int tile = blockIdx.x; tile < ntiles; tile += gridDim.x) {
        int e0 = tile * MS_TILE;
        int e1 = min(e0 + MS_TILE, E);

        hist[t] = 0; hist[t + 256] = 0;
        __syncthreads();
        for (int e = e0 + t; e < e1; e += 256) {
            int d = eidx[(size_t)(E + e) * st];
            atomicAdd(&hist[d >> BSH], 1);
        }
        __syncthreads();
        for (int b = t; b < NB; b += 256)
            if (hist[b] > 0) base[b] = atomicAdd(&binCursor[b], hist[b]);
        __syncthreads();
        hist[t] = 0; hist[t + 256] = 0;   // reuse as rank counters
        __syncthreads();
        for (int e = e0 + t; e < e1; e += 256) {
            int s = eidx[(size_t)e * st];
            int d = eidx[(size_t)(E + e) * st];
            int b = d >> BSH;
            int r = atomicAdd(&hist[b], 1);
            int local = base[b] + r;
            if (local < cap) {
                binned[(size_t)b * cap + local] =
                    ((unsigned int)s << BSH) | (unsigned int)(d & (BINSZ - 1));
            } else {
                int o = atomicAdd(ovfCnt, 1);
                if (o < OVF_CAP) ovf[o] = (v2i){s, d};
            }
        }
        __syncthreads();
    }
}

// ---------- exclusive scan of bin totals -> binBase ----------
__global__ __launch_bounds__(512) void k_binscan(const int* __restrict__ binCursor,
                                                 int* __restrict__ binBase,
                                                 int NB, int cap) {
    __shared__ int sh[512];
    int t = threadIdx.x;
    int v = (t < NB) ? min(binCursor[t], cap) : 0;
    sh[t] = v;
    __syncthreads();
    for (int d = 1; d < 512; d <<= 1) {
        int add = (t >= d) ? sh[t - d] : 0;
        __syncthreads();
        sh[t] += add;
        __syncthreads();
    }
    if (t < NB) binBase[t] = sh[t] - v;
}

// ---------- fused fill: hist + scan -> offsets/dinv/cursor; stage + flush csr ----------
// Plain (cacheable) loads: binned is read twice, second pass must be L2-hot
// (R13 used nt/evict-first -> refetched from HBM).
__global__ __launch_bounds__(256) void k_fillA(const unsigned int* __restrict__ binned,
                                               const int* __restrict__ binCursor,
                                               const int* __restrict__ binBase,
                                               int* __restrict__ offsets,
                                               int* __restrict__ cursor,
                                               float* __restrict__ dinv,
                                               int* __restrict__ csr,
                                               int cap, int N) {
    __shared__ int hist[BINSZ], scanS[BINSZ], curL[BINSZ];
    __shared__ unsigned int stage[CAPL];
    int b = blockIdx.x;
    int t = threadIdx.x;
    int g0 = b << BSH;
    int g = g0 + t;
    int n = min(binCursor[b], cap);
    const unsigned int* p = binned + (size_t)b * cap;

    hist[t] = 0;
    __syncthreads();
    for (int i = t; i < n; i += 256)
        atomicAdd(&hist[p[i] & (BINSZ - 1)], 1);
    __syncthreads();
    int h = hist[t];
    scanS[t] = h;
    __syncthreads();
    for (int d = 1; d < 256; d <<= 1) {
        int add = (t >= d) ? scanS[t - d] : 0;
        __syncthreads();
        scanS[t] += add;
        __syncthreads();
    }
    int excl = scanS[t] - h;
    int gbase = binBase[b];
    if (g < N) {
        offsets[g] = gbase + excl;
        dinv[g] = rsqrtf((float)(h + 1));
    }
    if (t == 255) offsets[min(g0 + BINSZ, N)] = gbase + scanS[255];  // race-benign dup

    curL[t] = excl;
    __syncthreads();
    int nl = min(n, CAPL);
    for (int i = t; i < nl; i += 256) {
        unsigned int w = p[i];
        int pos = atomicAdd(&curL[w & (BINSZ - 1)], 1);
        if (pos < CAPL) stage[pos] = w >> BSH;
    }
    __syncthreads();
    if (g < N) cursor[g] = gbase + curL[t];     // final positions (ovf valve)
    for (int i = t; i < nl; i += 256)
        csr[gbase + i] = (int)stage[i];         // coalesced flush
    __syncthreads();
    for (int i = CAPL + t; i < n; i += 256) {   // dead by construction
        unsigned int w = p[i];
        int pos = atomicAdd(&cursor[g0 + (int)(w & (BINSZ - 1))], 1);
        csr[pos] = (int)(w >> BSH);
    }
}

// ---------- drain overflow valve (normally 0 edges) ----------
__global__ void k_ovf(const int* __restrict__ ovfCnt, const v2i* __restrict__ ovf,
                      int* __restrict__ cursor, int* __restrict__ csr) {
    int n = min(*ovfCnt, OVF_CAP);
    for (int i = threadIdx.x; i < n; i += 256) {
        v2i e = ovf[i];
        int pos = atomicAdd(&cursor[e.y], 1);
        csr[pos] = e.x;
    }
}

// ---------- GEMM1: h1' = (x @ W1) * dinv[row], fp16-packed [N,32] __half2 ----------
__global__ __launch_bounds__(256) void k_gemm1t(const float* __restrict__ x,
                                                const float* __restrict__ W,
                                                const float* __restrict__ dinv,
                                                __half2* __restrict__ h1, int N) {
    __shared__ float xsT[DIM_IN * 64];      // [k][row] transposed tile, 32KB
    __shared__ float Ws[DIM_IN * DIM_HID];  // [k][col], 32KB
    int t = threadIdx.x;
    int row0 = blockIdx.x * 64;

#pragma unroll
    for (int i = 0; i < 8; i++)
        ((float4*)Ws)[t + 256 * i] = ((const float4*)W)[t + 256 * i];

#pragma unroll
    for (int i = 0; i < 8; i++) {
        int idx = t * 8 + i;
        int r = idx >> 5;
        int kc = idx & 31;
        int row = row0 + r;
        float4 v = (row < N) ? ((const float4*)(x + (size_t)row * DIM_IN))[kc]
                             : make_float4(0.f, 0.f, 0.f, 0.f);
        xsT[(4 * kc + 0) * 64 + r] = v.x;
        xsT[(4 * kc + 1) * 64 + r] = v.y;
        xsT[(4 * kc + 2) * 64 + r] = v.z;
        xsT[(4 * kc + 3) * 64 + r] = v.w;
    }
    __syncthreads();

    int c = t & 15;
    int r = t >> 4;
    float acc[4][4] = {};

#pragma unroll 4
    for (int k = 0; k < DIM_IN; k++) {
        float4 xa = *(const float4*)&xsT[k * 64 + 4 * r];
        float4 wb = *(const float4*)&Ws[k * DIM_HID + 4 * c];
#pragma unroll
        for (int i = 0; i < 4; i++) {
            float xi = (i == 0) ? xa.x : (i == 1) ? xa.y : (i == 2) ? xa.z : xa.w;
            acc[i][0] = fmaf(xi, wb.x, acc[i][0]);
            acc[i][1] = fmaf(xi, wb.y, acc[i][1]);
            acc[i][2] = fmaf(xi, wb.z, acc[i][2]);
            acc[i][3] = fmaf(xi, wb.w, acc[i][3]);
        }
    }

#pragma unroll
    for (int i = 0; i < 4; i++) {
        int row = row0 + 4 * r + i;
        if (row < N) {
            float d = dinv[row];
            h1[(size_t)row * 32 + 2 * c] = __floats2half2_rn(acc[i][0] * d, acc[i][1] * d);
            h1[(size_t)row * 32 + 2 * c + 1] = __floats2half2_rn(acc[i][2] * d, acc[i][3] * d);
        }
    }
}

// ---------- agg1: g = relu(di*(sum h1'[src] + h1'[node]) + b1); h2' = (g@W2)*di ----------
// Half-wave per node, coalesced csr load + __shfl broadcast, __hadd2 accum.
// (L2-miss-traffic bound at ~156MB/dispatch -- near structural, see R13 notes.)
__global__ __launch_bounds__(256) void k_agg1(const __half2* __restrict__ h1,
                                              const int* __restrict__ csr,
                                              const int* __restrict__ offsets,
                                              const float* __restrict__ dinv,
                                              const float* __restrict__ b1,
                                              const float* __restrict__ W2,
                                              float4* __restrict__ h2, int N) {
    int t = threadIdx.x;
    int hl = t & 31;
    int node = blockIdx.x * 8 + (t >> 5);
    if (node >= N) return;

    float di = dinv[node];
    int beg = offsets[node], end = offsets[node + 1];
    __half2 a0 = h1[(size_t)node * 32 + hl];   // self-loop (pre-scaled)
    __half2 a1 = __floats2half2_rn(0.f, 0.f);

    for (int base = beg; base < end; base += 32) {
        int rem = min(32, end - base);
        int sidx = (hl < rem) ? csr[base + hl] : 0;
        if (rem == 32) {
#pragma unroll 8
            for (int j = 0; j < 32; j += 4) {
                int s0 = __shfl(sidx, j, 32);
                int s1 = __shfl(sidx, j + 1, 32);
                int s2 = __shfl(sidx, j + 2, 32);
                int s3 = __shfl(sidx, j + 3, 32);
                a0 = __hadd2(a0, h1[(size_t)s0 * 32 + hl]);
                a1 = __hadd2(a1, h1[(size_t)s1 * 32 + hl]);
                a0 = __hadd2(a0, h1[(size_t)s2 * 32 + hl]);
                a1 = __hadd2(a1, h1[(size_t)s3 * 32 + hl]);
            }
        } else {
            int j = 0;
            for (; j + 1 < rem; j += 2) {
                int s0 = __shfl(sidx, j, 32);
                int s1 = __shfl(sidx, j + 1, 32);
                a0 = __hadd2(a0, h1[(size_t)s0 * 32 + hl]);
                a1 = __hadd2(a1, h1[(size_t)s1 * 32 + hl]);
            }
            if (j < rem) {
                int s0 = __shfl(sidx, j, 32);
                a0 = __hadd2(a0, h1[(size_t)s0 * 32 + hl]);
            }
        }
    }

    float2 f0 = __half22float2(a0);
    float2 f1 = __half22float2(a1);
    float accx = f0.x + f1.x, accy = f0.y + f1.y;

    float2 bb = ((const float2*)b1)[hl];
    float gx = fmaxf(fmaf(accx, di, bb.x), 0.f);
    float gy = fmaxf(fmaf(accy, di, bb.y), 0.f);

    const float* w0 = W2 + (2 * hl) * 3;
    const float* w1 = W2 + (2 * hl + 1) * 3;
    float v0 = gx * w0[0] + gy * w1[0];
    float v1 = gx * w0[1] + gy * w1[1];
    float v2 = gx * w0[2] + gy * w1[2];
#pragma unroll
    for (int off = 16; off > 0; off >>= 1) {
        v0 += __shfl_xor(v0, off, 64);
        v1 += __shfl_xor(v1, off, 64);
        v2 += __shfl_xor(v2, off, 64);
    }
    if (hl == 0) h2[node] = make_float4(v0 * di, v1 * di, v2 * di, 0.f);
}

// ---------- agg2: out = di*(sum h2'[src] + h2'[node]) + b2 ----------
// R14: 8 lanes/node (was 64) -- all 64 lanes issue independent 16B gathers
// from the L2-resident h2 (1.6MB); width-8 shuffle reduce.
__global__ __launch_bounds__(256) void k_agg2(const float4* __restrict__ h2,
                                              const int* __restrict__ csr,
                                              const int* __restrict__ offsets,
                                              const float* __restrict__ dinv,
                                              const float* __restrict__ b2,
                                              float* __restrict__ out, int N) {
    int t = threadIdx.x;
    int l = t & 7;
    int node = blockIdx.x * 32 + (t >> 3);
    if (node >= N) return;

    float di = dinv[node];
    int beg = offsets[node], end = offsets[node + 1];
    float a0 = 0.f, a1 = 0.f, a2 = 0.f;
    for (int e = beg + l; e < end; e += 8) {
        float4 h = h2[csr[e]];
        a0 += h.x;
        a1 += h.y;
        a2 += h.z;
    }
#pragma unroll
    for (int off = 4; off > 0; off >>= 1) {
        a0 += __shfl_xor(a0, off, 8);
        a1 += __shfl_xor(a1, off, 8);
        a2 += __shfl_xor(a2, off, 8);
    }
    if (l == 0) {
        float4 hs = h2[node];
        out[(size_t)node * 3 + 0] = fmaf(a0 + hs.x, di, b2[0]);
        out[(size_t)node * 3 + 1] = fmaf(a1 + hs.y, di, b2[1]);
        out[(size_t)node * 3 + 2] = fmaf(a2 + hs.z, di, b2[2]);
    }
}

extern "C" void kernel_launch(void* const* d_in, const int* in_sizes, int n_in,
                              void* d_out, int out_size, void* d_ws, size_t ws_size,
                              hipStream_t stream) {
    const float* x = (const float*)d_in[0];
    const int* eidx = (const int*)d_in[1];
    const float* W1 = (const float*)d_in[2];
    const float* b1 = (const float*)d_in[3];
    const float* W2 = (const float*)d_in[4];
    const float* b2 = (const float*)d_in[5];
    float* out = (float*)d_out;

    const int N = in_sizes[0] / DIM_IN;     // 100000
    const int E = in_sizes[1] / 2;          // 3200000
    const int NB = (N + BINSZ - 1) >> BSH;  // 391 bins of 256 nodes

    char* w = (char*)d_ws;
    size_t off = 0;
    auto carve = [&](size_t bytes) -> char* {
        char* p = w + off;
        off += (bytes + 255) & ~(size_t)255;
        return p;
    };
    int* offsets = (int*)carve((size_t)(N + 1) * 4);
    int* cursor = (int*)carve((size_t)N * 4);
    float* dinv = (float*)carve((size_t)N * 4);
    int* csr = (int*)carve((size_t)E * 4);
    int* binCursor = (int*)carve(MAXNB * 4);
    int* ovfCnt = (int*)carve(16);
    v2i* ovf = (v2i*)carve((size_t)OVF_CAP * 8);
    int* binBase = (int*)carve(MAXNB * 4);
    float4* h2 = (float4*)carve((size_t)N * 16);

    // uni region: packed binned words (msplit..fillA), then aliased by fp16 h1'.
    size_t h1_bytes = (size_t)N * DIM_HID * 2;
    int capDes = E / NB + E / NB / 16 + 128;     // mean + margin; < CAPL by construction
    size_t binned_des = (size_t)NB * capDes * 4;
    size_t uni_avail = (ws_size > off + 256) ? (ws_size - off - 256) : h1_bytes;
    size_t uni_bytes = binned_des > h1_bytes ? binned_des : h1_bytes;
    if (uni_bytes > uni_avail) uni_bytes = uni_avail > h1_bytes ? uni_avail : h1_bytes;
    char* uni = carve(uni_bytes);
    unsigned int* binned = (unsigned int*)uni;
    __half2* h1 = (__half2*)uni;        // aliased: valid only after k_fillA
    int cap = (int)(uni_bytes / ((size_t)NB * 4));
    if (cap > capDes) cap = capDes;
    if (cap > CAPL) cap = CAPL;         // keep the fillA stage invariant

    (void)hipMemsetAsync(binCursor, 0, MAXNB * 4 + 256, stream);  // binCursor + ovfCnt

    int ntiles = (E + MS_TILE - 1) / MS_TILE;
    k_msplit3<<<ntiles, 256, 0, stream>>>(eidx, binCursor, binned, ovfCnt, ovf,
                                          E, NB, cap);
    k_binscan<<<1, 512, 0, stream>>>(binCursor, binBase, NB, cap);
    k_fillA<<<NB, 256, 0, stream>>>(binned, binCursor, binBase, offsets, cursor,
                                    dinv, csr, cap, N);
    k_ovf<<<1, 256, 0, stream>>>(ovfCnt, ovf, cursor, csr);

    k_gemm1t<<<(N + 63) / 64, 256, 0, stream>>>(x, W1, dinv, h1, N);
    k_agg1<<<(N + 7) / 8, 256, 0, stream>>>(h1, csr, offsets, dinv, b1, W2, h2, N);
    k_agg2<<<(N + 31) / 32, 256, 0, stream>>>(h2, csr, offsets, dinv, b2, out, N);
}